// Round 1
// baseline (729.010 us; speedup 1.0000x reference)
//
#include <hip/hip_runtime.h>
#include <math.h>

#define D 256
#define NX 16
#define L 2048
#define NBATCH 8
#define NTOK (NBATCH * L)

__device__ __forceinline__ void block_reduce2(float& a, float& b, float* red) {
  #pragma unroll
  for (int off = 32; off; off >>= 1) {
    a += __shfl_xor(a, off);
    b += __shfl_xor(b, off);
  }
  int w = threadIdx.x >> 6;
  if ((threadIdx.x & 63) == 0) { red[w] = a; red[4 + w] = b; }
  __syncthreads();
  a = red[0] + red[1] + red[2] + red[3];
  b = red[4] + red[5] + red[6] + red[7];
  __syncthreads();
}

// K1: per-token front end: h = y@Win + bin; hn = LN(h); delta; Bm; Cm
__global__ __launch_bounds__(256) void k1_front(
    const float* __restrict__ y, const float* __restrict__ Win,
    const float* __restrict__ bin_, const float* __restrict__ ng,
    const float* __restrict__ nb, const float* __restrict__ WB,
    const float* __restrict__ WC, const float* __restrict__ qd,
    const float* __restrict__ pd,
    float* __restrict__ h, float* __restrict__ hn,
    float* __restrict__ delta, float* __restrict__ Bm, float* __restrict__ Cm) {
  __shared__ float sy[32];
  __shared__ float s_hn[D];
  __shared__ float red[8];
  int tok = blockIdx.x;
  int d = threadIdx.x;
  if (d < 32) sy[d] = y[tok * 32 + d];
  __syncthreads();
  float acc = bin_[d];
  #pragma unroll
  for (int p = 0; p < 32; ++p) acc = fmaf(sy[p], Win[p * D + d], acc);
  h[tok * D + d] = acc;
  float s1 = acc, s2 = acc * acc;
  block_reduce2(s1, s2, red);
  float mu = s1 * (1.f / D);
  float var = s2 * (1.f / D) - mu * mu;
  float rstd = rsqrtf(var + 1e-5f);
  float v = (acc - mu) * rstd * ng[d] + nb[d];
  hn[tok * D + d] = v;
  s_hn[d] = v;
  float dd = v * qd[d], dummy = 0.f;
  block_reduce2(dd, dummy, red);  // ends with syncthreads -> s_hn visible
  if (d == 0) {
    float xx = pd[0] + dd;
    delta[tok] = (xx > 20.f) ? xx : log1pf(expf(xx));  // softplus
  }
  // Bm[n] = sum_d WB[n,d]*hn[d]; thread -> (n = d>>4, sub = d&15), 16 d's each
  int n = d >> 4, sub = d & 15;
  float pB = 0.f, pC = 0.f;
  #pragma unroll
  for (int j = 0; j < 16; ++j) {
    float hv = s_hn[sub * 16 + j];
    pB = fmaf(WB[n * D + sub * 16 + j], hv, pB);
    pC = fmaf(WC[n * D + sub * 16 + j], hv, pC);
  }
  #pragma unroll
  for (int off = 8; off; off >>= 1) {
    pB += __shfl_xor(pB, off);
    pC += __shfl_xor(pC, off);
  }
  if (sub == 0) { Bm[tok * NX + n] = pB; Cm[tok * NX + n] = pC; }
}

// K2: selective scan. Block = (b, dgroup of 16 d's); thread = (d_local, n).
// Writes hf = h + upd in-place into h.
__global__ __launch_bounds__(256) void k2_scan(
    const float* __restrict__ hn, const float* __restrict__ delta,
    const float* __restrict__ Bm, const float* __restrict__ Cm,
    const float* __restrict__ A, float* __restrict__ h) {
  __shared__ float sdelta[64];
  __shared__ float sB[64][NX];
  __shared__ float sC[64][NX];
  __shared__ float shn[64][16];
  __shared__ float sh[64][16];
  __shared__ float sy[64][16];
  int b = blockIdx.x >> 4;
  int dg = blockIdx.x & 15;
  int t = threadIdx.x;
  int dl = t >> 4, n = t & 15;
  int d = dg * 16 + dl;
  float Ad2 = A[d * NX + n] * 1.44269504088896340736f;  // A * log2(e)
  float x = 0.f;
  for (int l0 = 0; l0 < L; l0 += 64) {
    if (t < 64) sdelta[t] = delta[b * L + l0 + t];
    for (int i = t; i < 64 * NX; i += 256) {
      ((float*)sB)[i] = Bm[(b * L + l0) * NX + i];
      ((float*)sC)[i] = Cm[(b * L + l0) * NX + i];
    }
    for (int i = t; i < 64 * 16; i += 256) {
      int lo = i >> 4, dd = i & 15;
      int gidx = (b * L + l0 + lo) * D + dg * 16 + dd;
      ((float*)shn)[i] = hn[gidx];
      ((float*)sh)[i] = h[gidx];
    }
    __syncthreads();
    for (int lo = 0; lo < 64; ++lo) {
      float dlt = sdelta[lo];
      float hv = shn[lo][dl];
      float bm = sB[lo][n];
      float cm = sC[lo][n];
      float dA = exp2f(dlt * Ad2);
      x = fmaf(dA, x, dlt * hv * bm);
      float p = x * cm;
      p += __shfl_xor(p, 1);
      p += __shfl_xor(p, 2);
      p += __shfl_xor(p, 4);
      p += __shfl_xor(p, 8);
      if (n == 0) sy[lo][dl] = sh[lo][dl] + p;
    }
    __syncthreads();
    for (int i = t; i < 64 * 16; i += 256) {
      int lo = i >> 4, dd = i & 15;
      h[(b * L + l0 + lo) * D + dg * 16 + dd] = sy[lo][dd];
    }
    __syncthreads();
  }
}

// K3a: second layernorm
__global__ __launch_bounds__(256) void k3a_ln(
    const float* __restrict__ hf, const float* __restrict__ nfg,
    const float* __restrict__ nfb, float* __restrict__ hn2) {
  __shared__ float red[8];
  int tok = blockIdx.x, d = threadIdx.x;
  float v = hf[tok * D + d];
  float s1 = v, s2 = v * v;
  block_reduce2(s1, s2, red);
  float mu = s1 * (1.f / D);
  float var = s2 * (1.f / D) - mu * mu;
  hn2[tok * D + d] = (v - mu) * rsqrtf(var + 1e-5f) * nfg[d] + nfb[d];
}

__device__ __forceinline__ float gelu_exact(float x) {
  return 0.5f * x * (1.f + erff(x * 0.70710678118654752440f));
}

// K3b: out = gelu(hn2@W1 + b1)@W2 + b2.  Block: 32 tokens; thread: 8 tok x 4 cols.
__global__ __launch_bounds__(256) void k3b_mlp(
    const float* __restrict__ hn2, const float* __restrict__ W1,
    const float* __restrict__ b1, const float* __restrict__ W2,
    const float* __restrict__ b2, float* __restrict__ out) {
  __shared__ float s_az[32 * 260];  // a[32][256] then z[32][260]
  __shared__ float s_w[32 * 256];   // W1 k-tile, then W2
  int t = threadIdx.x;
  int tok0 = blockIdx.x * 32;
  // stage a (hn2 tile, token-major)
  {
    const float4* src = (const float4*)(hn2 + tok0 * D);
    float4* dst = (float4*)s_az;
    for (int i = t; i < 2048; i += 256) dst[i] = src[i];
  }
  float4 acc[8];
  #pragma unroll
  for (int jj = 0; jj < 8; ++jj) acc[jj] = make_float4(0.f, 0.f, 0.f, 0.f);
  int dcol = t & 63, jrow = t >> 6;
  int d4 = dcol * 4, j8 = jrow * 8;
  for (int kb = 0; kb < 256; kb += 32) {
    __syncthreads();  // protect s_w reuse (and a-stage on first iter)
    {
      const float4* wsrc = (const float4*)(W1 + kb * D);
      float4* wdst = (float4*)s_w;
      for (int i = t; i < 2048; i += 256) wdst[i] = wsrc[i];
    }
    __syncthreads();
    #pragma unroll 8
    for (int k = 0; k < 32; ++k) {
      float4 w = *(float4*)&s_w[k * D + d4];
      #pragma unroll
      for (int jj = 0; jj < 8; ++jj) {
        float av = s_az[(j8 + jj) * 256 + kb + k];  // wave-uniform broadcast
        acc[jj].x = fmaf(av, w.x, acc[jj].x);
        acc[jj].y = fmaf(av, w.y, acc[jj].y);
        acc[jj].z = fmaf(av, w.z, acc[jj].z);
        acc[jj].w = fmaf(av, w.w, acc[jj].w);
      }
    }
  }
  float4 b1v = *(const float4*)&b1[d4];
  __syncthreads();  // all k-loop reads of s_az done
  #pragma unroll
  for (int jj = 0; jj < 8; ++jj) {
    float4 v = acc[jj];
    v.x = gelu_exact(v.x + b1v.x);
    v.y = gelu_exact(v.y + b1v.y);
    v.z = gelu_exact(v.z + b1v.z);
    v.w = gelu_exact(v.w + b1v.w);
    *(float4*)&s_az[(j8 + jj) * 260 + d4] = v;  // z, pitch 260
  }
  {
    const float4* w2s = (const float4*)W2;
    float4* wdst = (float4*)s_w;
    for (int i = t; i < 2048; i += 256) wdst[i] = w2s[i];
  }
  __syncthreads();
  // stage 3: out[j][p] = sum_d z[j][d] * W2[d][p]
  int j = t >> 3, p4 = (t & 7) * 4;
  float4 o = make_float4(0.f, 0.f, 0.f, 0.f);
  for (int dd = 0; dd < 256; ++dd) {
    float zv = s_az[j * 260 + dd];
    float4 w = *(float4*)&s_w[dd * 32 + p4];
    o.x = fmaf(zv, w.x, o.x);
    o.y = fmaf(zv, w.y, o.y);
    o.z = fmaf(zv, w.z, o.z);
    o.w = fmaf(zv, w.w, o.w);
  }
  float4 b2v = *(const float4*)&b2[p4];
  o.x += b2v.x; o.y += b2v.y; o.z += b2v.z; o.w += b2v.w;
  *(float4*)&out[(tok0 + j) * 32 + p4] = o;
}

extern "C" void kernel_launch(void* const* d_in, const int* in_sizes, int n_in,
                              void* d_out, int out_size, void* d_ws, size_t ws_size,
                              hipStream_t stream) {
  const float* y    = (const float*)d_in[0];
  const float* Win  = (const float*)d_in[1];
  const float* bin_ = (const float*)d_in[2];
  const float* ng   = (const float*)d_in[3];
  const float* nb   = (const float*)d_in[4];
  const float* A    = (const float*)d_in[5];
  const float* WB   = (const float*)d_in[6];
  const float* WC   = (const float*)d_in[7];
  const float* qd   = (const float*)d_in[8];
  const float* pd   = (const float*)d_in[9];
  const float* nfg  = (const float*)d_in[10];
  const float* nfb  = (const float*)d_in[11];
  const float* W1   = (const float*)d_in[12];
  const float* b1   = (const float*)d_in[13];
  const float* W2   = (const float*)d_in[14];
  const float* b2   = (const float*)d_in[15];

  float* ws = (float*)d_ws;
  float* h     = ws;                       // NTOK*D = 4194304 floats (becomes hf)
  float* hn    = ws + 4194304;             // NTOK*D (becomes hn2 after k3a)
  float* delta = ws + 8388608;             // NTOK
  float* Bm    = delta + NTOK;             // NTOK*NX
  float* Cm    = Bm + NTOK * NX;           // NTOK*NX

  k1_front<<<NTOK, 256, 0, stream>>>(y, Win, bin_, ng, nb, WB, WC, qd, pd,
                                     h, hn, delta, Bm, Cm);
  k2_scan<<<NBATCH * 16, 256, 0, stream>>>(hn, delta, Bm, Cm, A, h);
  k3a_ln<<<NTOK, 256, 0, stream>>>(h, nfg, nfb, hn);
  k3b_mlp<<<NTOK / 32, 256, 0, stream>>>(hn, W1, b1, W2, b2, (float*)d_out);
}

// Round 2
// 315.751 us; speedup vs baseline: 2.3088x; 2.3088x over previous
//
#include <hip/hip_runtime.h>
#include <math.h>

#define D 256
#define NX 16
#define L 2048
#define NBATCH 8
#define NTOK (NBATCH * L)
#define CL 64
#define NCH (L / CL)  // 32
#define LOG2E 1.44269504088896340736f

__device__ __forceinline__ void block_reduce2(float& a, float& b, float* red) {
  #pragma unroll
  for (int off = 32; off; off >>= 1) {
    a += __shfl_xor(a, off);
    b += __shfl_xor(b, off);
  }
  int w = threadIdx.x >> 6;
  if ((threadIdx.x & 63) == 0) { red[w] = a; red[4 + w] = b; }
  __syncthreads();
  a = red[0] + red[1] + red[2] + red[3];
  b = red[4] + red[5] + red[6] + red[7];
  __syncthreads();
}

// K1: per-token front end: h = y@Win + bin (reg only); hn = LN(h); delta; Bm; Cm
__global__ __launch_bounds__(256) void k1_front(
    const float* __restrict__ y, const float* __restrict__ Win,
    const float* __restrict__ bin_, const float* __restrict__ ng,
    const float* __restrict__ nb, const float* __restrict__ WB,
    const float* __restrict__ WC, const float* __restrict__ qd,
    const float* __restrict__ pd,
    float* __restrict__ hn, float* __restrict__ delta,
    float* __restrict__ Bm, float* __restrict__ Cm) {
  __shared__ float sy[32];
  __shared__ float s_hn[D];
  __shared__ float red[8];
  int tok = blockIdx.x;
  int d = threadIdx.x;
  if (d < 32) sy[d] = y[tok * 32 + d];
  __syncthreads();
  float acc = bin_[d];
  #pragma unroll
  for (int p = 0; p < 32; ++p) acc = fmaf(sy[p], Win[p * D + d], acc);
  float s1 = acc, s2 = acc * acc;
  block_reduce2(s1, s2, red);
  float mu = s1 * (1.f / D);
  float var = s2 * (1.f / D) - mu * mu;
  float rstd = rsqrtf(var + 1e-5f);
  float v = (acc - mu) * rstd * ng[d] + nb[d];
  hn[tok * D + d] = v;
  s_hn[d] = v;
  float dd = v * qd[d], dummy = 0.f;
  block_reduce2(dd, dummy, red);  // ends with syncthreads -> s_hn visible
  if (d == 0) {
    float xx = pd[0] + dd;
    delta[tok] = (xx > 20.f) ? xx : log1pf(expf(xx));  // softplus
  }
  int n = d >> 4, sub = d & 15;
  float pB = 0.f, pC = 0.f;
  #pragma unroll
  for (int j = 0; j < 16; ++j) {
    float hv = s_hn[sub * 16 + j];
    pB = fmaf(WB[n * D + sub * 16 + j], hv, pB);
    pC = fmaf(WC[n * D + sub * 16 + j], hv, pC);
  }
  #pragma unroll
  for (int off = 8; off; off >>= 1) {
    pB += __shfl_xor(pB, off);
    pC += __shfl_xor(pC, off);
  }
  if (sub == 0) { Bm[tok * NX + n] = pB; Cm[tok * NX + n] = pC; }
}

// K2a: local chunk scans from zero state. Block=(b,chunk,dgroup of 16 d's),
// thread=(dl,n). Writes y_partial (over hn buffer), chunk end state E (into EX),
// within-chunk inclusive delta cumsum S, chunk delta totals T.
__global__ __launch_bounds__(256) void k2a_local(
    const float* __restrict__ hn, const float* __restrict__ delta,
    const float* __restrict__ Bm, const float* __restrict__ Cm,
    const float* __restrict__ A,
    float* __restrict__ ypart, float* __restrict__ EX,
    float* __restrict__ S, float* __restrict__ T) {
  __shared__ float sdelta[CL];
  __shared__ float sB[CL][NX];
  __shared__ float sC[CL][NX];
  __shared__ float shn[CL][16];
  __shared__ float sy[CL][16];
  int blk = blockIdx.x;
  int dg = blk & 15;
  int ch = (blk >> 4) & (NCH - 1);
  int b = blk >> 9;
  int t = threadIdx.x;
  int dl = t >> 4, n = t & 15;
  int d = dg * 16 + dl;
  int l0 = ch * CL;
  float Ad2 = A[d * NX + n] * LOG2E;
  if (t < CL) sdelta[t] = delta[b * L + l0 + t];
  for (int i = t; i < CL * NX; i += 256) {
    ((float*)sB)[i] = Bm[(b * L + l0) * NX + i];
    ((float*)sC)[i] = Cm[(b * L + l0) * NX + i];
  }
  for (int i = t; i < CL * 16; i += 256) {
    int lo = i >> 4, dd = i & 15;
    ((float*)shn)[i] = hn[(b * L + l0 + lo) * D + dg * 16 + dd];
  }
  __syncthreads();
  if (t < CL) {  // wave 0: inclusive scan of delta
    float v = sdelta[t];
    #pragma unroll
    for (int off = 1; off < CL; off <<= 1) {
      float u = __shfl_up(v, off);
      if (t >= off) v += u;
    }
    S[b * L + l0 + t] = v;
    if (t == CL - 1) T[b * NCH + ch] = v;
  }
  float x = 0.f;
  for (int lo = 0; lo < CL; ++lo) {
    float dlt = sdelta[lo];
    float dA = exp2f(dlt * Ad2);
    x = fmaf(dA, x, dlt * shn[lo][dl] * sB[lo][n]);
    float p = x * sC[lo][n];
    p += __shfl_xor(p, 1);
    p += __shfl_xor(p, 2);
    p += __shfl_xor(p, 4);
    p += __shfl_xor(p, 8);
    if (n == 0) sy[lo][dl] = p;
  }
  EX[((b * NCH + ch) * D + d) * NX + n] = x;
  __syncthreads();
  for (int i = t; i < CL * 16; i += 256) {
    int lo = i >> 4, dd = i & 15;
    ypart[(b * L + l0 + lo) * D + dg * 16 + dd] = sy[lo][dd];
  }
}

// K2b: chunk-level scan. Thread owns (b,d,n); in-place E -> X (state entering
// each chunk). X_c = exp(A*T_{c-1}) * X_{c-1} + E_{c-1}.
__global__ __launch_bounds__(256) void k2b_chunkscan(
    const float* __restrict__ A, const float* __restrict__ T,
    float* __restrict__ EX) {
  __shared__ float sT[NCH];
  int g = blockIdx.x * 256 + threadIdx.x;
  int b = g >> 12;       // D*NX = 4096
  int rem = g & 4095;    // = d*NX + n
  if (threadIdx.x < NCH) sT[threadIdx.x] = T[b * NCH + threadIdx.x];
  __syncthreads();
  float Ad2 = A[rem] * LOG2E;
  float x = 0.f;
  for (int c = 0; c < NCH; ++c) {
    size_t idx = ((size_t)(b * NCH + c) << 12) + rem;
    float e = EX[idx];
    EX[idx] = x;                       // X_c (state entering chunk c)
    x = fmaf(exp2f(sT[c] * Ad2), x, e);
  }
}

// K2c: per-token fixup + LN2 fused. hf = (y@Win+bin) + ypart + C . (exp(A*S)*X)
// then layernorm -> hn2 (written over ypart/hn buffer).
__global__ __launch_bounds__(256) void k2c_fused(
    const float* __restrict__ y, const float* __restrict__ Win,
    const float* __restrict__ bin_,
    const float* __restrict__ ypart, const float* __restrict__ Cm,
    const float* __restrict__ S, const float* __restrict__ EX,
    const float* __restrict__ A,
    const float* __restrict__ nfg, const float* __restrict__ nfb,
    float* __restrict__ hn2) {
  __shared__ float sy32[32];
  __shared__ float sCn[NX];
  __shared__ float sSl;
  __shared__ float red[8];
  int tok = blockIdx.x;
  int b = tok >> 11;   // L = 2048
  int l = tok & 2047;
  int ch = l >> 6;
  int d = threadIdx.x;
  if (d < 32) sy32[d] = y[tok * 32 + d];
  if (d < NX) sCn[d] = Cm[tok * NX + d];
  if (d == 32) sSl = S[tok];
  __syncthreads();
  float acc = bin_[d];
  #pragma unroll
  for (int p = 0; p < 32; ++p) acc = fmaf(sy32[p], Win[p * D + d], acc);
  float Sl = sSl;
  const float4* Arow = (const float4*)(A + d * NX);
  const float4* Xrow = (const float4*)(EX + (((size_t)(b * NCH + ch) * D + d) << 4));
  float corr = 0.f;
  #pragma unroll
  for (int q = 0; q < 4; ++q) {
    float4 a4 = Arow[q];
    float4 x4 = Xrow[q];
    corr = fmaf(sCn[q * 4 + 0] * x4.x, exp2f(a4.x * (LOG2E * 1.0f) * Sl), corr);
    corr = fmaf(sCn[q * 4 + 1] * x4.y, exp2f(a4.y * (LOG2E * 1.0f) * Sl), corr);
    corr = fmaf(sCn[q * 4 + 2] * x4.z, exp2f(a4.z * (LOG2E * 1.0f) * Sl), corr);
    corr = fmaf(sCn[q * 4 + 3] * x4.w, exp2f(a4.w * (LOG2E * 1.0f) * Sl), corr);
  }
  float hf = acc + ypart[tok * D + d] + corr;
  float s1 = hf, s2 = hf * hf;
  block_reduce2(s1, s2, red);
  float mu = s1 * (1.f / D);
  float var = s2 * (1.f / D) - mu * mu;
  hn2[tok * D + d] = (hf - mu) * rsqrtf(var + 1e-5f) * nfg[d] + nfb[d];
}

__device__ __forceinline__ float gelu_exact(float x) {
  return 0.5f * x * (1.f + erff(x * 0.70710678118654752440f));
}

// K3b: out = gelu(hn2@W1 + b1)@W2 + b2.  Block: 32 tokens; thread: 8 tok x 4 cols.
__global__ __launch_bounds__(256) void k3b_mlp(
    const float* __restrict__ hn2, const float* __restrict__ W1,
    const float* __restrict__ b1, const float* __restrict__ W2,
    const float* __restrict__ b2, float* __restrict__ out) {
  __shared__ float s_az[32 * 260];  // a[32][256] then z[32][260]
  __shared__ float s_w[32 * 256];   // W1 k-tile, then W2
  int t = threadIdx.x;
  int tok0 = blockIdx.x * 32;
  {
    const float4* src = (const float4*)(hn2 + tok0 * D);
    float4* dst = (float4*)s_az;
    for (int i = t; i < 2048; i += 256) dst[i] = src[i];
  }
  float4 acc[8];
  #pragma unroll
  for (int jj = 0; jj < 8; ++jj) acc[jj] = make_float4(0.f, 0.f, 0.f, 0.f);
  int dcol = t & 63, jrow = t >> 6;
  int d4 = dcol * 4, j8 = jrow * 8;
  for (int kb = 0; kb < 256; kb += 32) {
    __syncthreads();
    {
      const float4* wsrc = (const float4*)(W1 + kb * D);
      float4* wdst = (float4*)s_w;
      for (int i = t; i < 2048; i += 256) wdst[i] = wsrc[i];
    }
    __syncthreads();
    #pragma unroll 8
    for (int k = 0; k < 32; ++k) {
      float4 w = *(float4*)&s_w[k * D + d4];
      #pragma unroll
      for (int jj = 0; jj < 8; ++jj) {
        float av = s_az[(j8 + jj) * 256 + kb + k];
        acc[jj].x = fmaf(av, w.x, acc[jj].x);
        acc[jj].y = fmaf(av, w.y, acc[jj].y);
        acc[jj].z = fmaf(av, w.z, acc[jj].z);
        acc[jj].w = fmaf(av, w.w, acc[jj].w);
      }
    }
  }
  float4 b1v = *(const float4*)&b1[d4];
  __syncthreads();
  #pragma unroll
  for (int jj = 0; jj < 8; ++jj) {
    float4 v = acc[jj];
    v.x = gelu_exact(v.x + b1v.x);
    v.y = gelu_exact(v.y + b1v.y);
    v.z = gelu_exact(v.z + b1v.z);
    v.w = gelu_exact(v.w + b1v.w);
    *(float4*)&s_az[(j8 + jj) * 260 + d4] = v;
  }
  {
    const float4* w2s = (const float4*)W2;
    float4* wdst = (float4*)s_w;
    for (int i = t; i < 2048; i += 256) wdst[i] = w2s[i];
  }
  __syncthreads();
  int j = t >> 3, p4 = (t & 7) * 4;
  float4 o = make_float4(0.f, 0.f, 0.f, 0.f);
  for (int dd = 0; dd < 256; ++dd) {
    float zv = s_az[j * 260 + dd];
    float4 w = *(float4*)&s_w[dd * 32 + p4];
    o.x = fmaf(zv, w.x, o.x);
    o.y = fmaf(zv, w.y, o.y);
    o.z = fmaf(zv, w.z, o.z);
    o.w = fmaf(zv, w.w, o.w);
  }
  float4 b2v = *(const float4*)&b2[p4];
  o.x += b2v.x; o.y += b2v.y; o.z += b2v.z; o.w += b2v.w;
  *(float4*)&out[(tok0 + j) * 32 + p4] = o;
}

extern "C" void kernel_launch(void* const* d_in, const int* in_sizes, int n_in,
                              void* d_out, int out_size, void* d_ws, size_t ws_size,
                              hipStream_t stream) {
  const float* y    = (const float*)d_in[0];
  const float* Win  = (const float*)d_in[1];
  const float* bin_ = (const float*)d_in[2];
  const float* ng   = (const float*)d_in[3];
  const float* nb   = (const float*)d_in[4];
  const float* A    = (const float*)d_in[5];
  const float* WB   = (const float*)d_in[6];
  const float* WC   = (const float*)d_in[7];
  const float* qd   = (const float*)d_in[8];
  const float* pd   = (const float*)d_in[9];
  const float* nfg  = (const float*)d_in[10];
  const float* nfb  = (const float*)d_in[11];
  const float* W1   = (const float*)d_in[12];
  const float* b1   = (const float*)d_in[13];
  const float* W2   = (const float*)d_in[14];
  const float* b2   = (const float*)d_in[15];

  float* ws = (float*)d_ws;
  float* hnbuf = ws;                         // NTOK*D; hn -> ypart -> hn2
  float* delta = ws + 4194304;               // NTOK
  float* Bm    = delta + NTOK;               // NTOK*NX
  float* Cm    = Bm + NTOK * NX;             // NTOK*NX
  float* Sbuf  = Cm + NTOK * NX;             // NTOK
  float* Tbuf  = Sbuf + NTOK;                // NBATCH*NCH
  float* EX    = Tbuf + NBATCH * NCH;        // NBATCH*NCH*D*NX

  k1_front<<<NTOK, 256, 0, stream>>>(y, Win, bin_, ng, nb, WB, WC, qd, pd,
                                     hnbuf, delta, Bm, Cm);
  k2a_local<<<NBATCH * NCH * 16, 256, 0, stream>>>(hnbuf, delta, Bm, Cm, A,
                                                   hnbuf, EX, Sbuf, Tbuf);
  k2b_chunkscan<<<NBATCH * D * NX / 256, 256, 0, stream>>>(A, Tbuf, EX);
  k2c_fused<<<NTOK, 256, 0, stream>>>(y, Win, bin_, hnbuf, Cm, Sbuf, EX, A,
                                      nfg, nfb, hnbuf);
  k3b_mlp<<<NTOK / 32, 256, 0, stream>>>(hnbuf, W1, b1, W2, b2, (float*)d_out);
}